// Round 1
// baseline (567.635 us; speedup 1.0000x reference)
//
#include <hip/hip_runtime.h>
#include <hip/hip_bf16.h>
#include <cstdint>
#include <cstddef>

#define T_TOK 4096
#define HID   1024
#define FFN   3584
#define NEXP  8
#define RTOT  (T_TOK * 2)   // total (token, slot) rows = T * top_k
#define MAXT  72            // max M-tiles: floor(8192/128) + 7 = 71, +1 slack
#define BM 128
#define BN 128
#define BK 32
#define APAD 40             // LDS row stride in bf16 elems (80B -> conflict-free b128 frag reads)

typedef __attribute__((ext_vector_type(8))) short bvec8;   // 8 x bf16 (4 VGPR) MFMA operand
typedef __attribute__((ext_vector_type(4))) short bvec4;
typedef __attribute__((ext_vector_type(4))) float fvec4;   // MFMA accumulator
typedef unsigned short u16;

__device__ __forceinline__ u16 f2b(float f) {
  __bf16 b = (__bf16)f;                 // RNE convert
  return __builtin_bit_cast(u16, b);
}

// ---------------- router: logits (fp32, exact), top-2, combine weights, expert counts ----
__global__ void router_kernel(const float* __restrict__ x, const float* __restrict__ gw,
                              float* __restrict__ logits, int* __restrict__ tk_id,
                              float* __restrict__ tk_w, int* __restrict__ counts, int full) {
  const int lane = threadIdx.x & 63;
  const int wid  = threadIdx.x >> 6;
  const int t = blockIdx.x * 4 + wid;          // one token per wave
  const float4* xr = (const float4*)(x + (size_t)t * HID);
  float acc[NEXP] = {0.f, 0.f, 0.f, 0.f, 0.f, 0.f, 0.f, 0.f};
#pragma unroll
  for (int it = 0; it < 4; ++it) {
    int k4 = it * 64 + lane;                   // float4 index, covers H/4 = 256
    float4 xv = xr[k4];
    const float* gp = gw + (size_t)k4 * 4 * NEXP;
    float xs[4] = {xv.x, xv.y, xv.z, xv.w};
#pragma unroll
    for (int kk = 0; kk < 4; ++kk) {
      float4 ga = ((const float4*)(gp + kk * NEXP))[0];
      float4 gb = ((const float4*)(gp + kk * NEXP))[1];
      acc[0] += xs[kk] * ga.x; acc[1] += xs[kk] * ga.y;
      acc[2] += xs[kk] * ga.z; acc[3] += xs[kk] * ga.w;
      acc[4] += xs[kk] * gb.x; acc[5] += xs[kk] * gb.y;
      acc[6] += xs[kk] * gb.z; acc[7] += xs[kk] * gb.w;
    }
  }
#pragma unroll
  for (int off = 32; off > 0; off >>= 1) {
#pragma unroll
    for (int e = 0; e < NEXP; ++e) acc[e] += __shfl_xor(acc[e], off, 64);
  }
  if (lane < NEXP) logits[(size_t)t * NEXP + lane] = acc[lane];
  if (full && lane == 0) {
    int e0 = 0; float l0 = acc[0];
#pragma unroll
    for (int e = 1; e < NEXP; ++e) if (acc[e] > l0) { l0 = acc[e]; e0 = e; }
    int e1 = -1; float l1 = -3.4e38f;
#pragma unroll
    for (int e = 0; e < NEXP; ++e) if (e != e0 && acc[e] > l1) { l1 = acc[e]; e1 = e; }
    // normalized top-2 softmax weights == softmax over {l0, l1}
    float w0 = 1.f / (1.f + expf(l1 - l0));
    float w1 = 1.f - w0;
    tk_id[t * 2 + 0] = e0; tk_id[t * 2 + 1] = e1;
    tk_w[t * 2 + 0] = w0;  tk_w[t * 2 + 1] = w1;
    atomicAdd(&counts[e0], 1); atomicAdd(&counts[e1], 1);
  }
}

// ---------------- scan: offsets, tile map (single thread; 8 experts, trivial) -----------
__global__ void scan_kernel(const int* __restrict__ counts, int* __restrict__ offsets,
                            int* __restrict__ cursors, int4* __restrict__ tilemap) {
  if (threadIdx.x != 0) return;
  int off = 0, nt = 0;
  for (int e = 0; e < NEXP; ++e) {
    offsets[e] = off; cursors[e] = 0;
    int c = counts[e];
    for (int tm = 0; tm * BM < c; ++tm)
      tilemap[nt++] = make_int4(e, off + tm * BM, min(BM, c - tm * BM), 0);
    off += c;
  }
  offsets[NEXP] = off;
  for (; nt < MAXT; ++nt) tilemap[nt] = make_int4(-1, 0, 0, 0);
}

// ---------------- scatter: build per-expert sorted row lists ----------------------------
__global__ void scatter_kernel(const int* __restrict__ tk_id, const float* __restrict__ tk_w,
                               const int* __restrict__ offsets, int* __restrict__ cursors,
                               int* __restrict__ rowmap, float* __restrict__ roww) {
  int i = blockIdx.x * 256 + threadIdx.x;      // 0 .. RTOT-1
  int t = i >> 1;
  int e = tk_id[i]; float w = tk_w[i];
  int p = atomicAdd(&cursors[e], 1);
  rowmap[offsets[e] + p] = t; roww[offsets[e] + p] = w;
}

// ---------------- cast x to bf16 --------------------------------------------------------
__global__ void cast_x_kernel(const float* __restrict__ x, u16* __restrict__ xb) {
  size_t i = (size_t)blockIdx.x * 256 + threadIdx.x;   // one float4 each
  float4 v = ((const float4*)x)[i];
  bvec4 o;
  o[0] = (short)f2b(v.x); o[1] = (short)f2b(v.y);
  o[2] = (short)f2b(v.z); o[3] = (short)f2b(v.w);
  *(bvec4*)(xb + i * 4) = o;
}

// ---------------- transpose + cast: fp32 [R][C] -> bf16 [C][R], batched by blockIdx.z ---
__global__ void transpose_cast_kernel(const float* __restrict__ src, u16* __restrict__ dst,
                                      int R, int C) {
  __shared__ __attribute__((aligned(16))) u16 tile[64][72];  // pad 72 (144B rows, 16B-mult)
  src += (size_t)blockIdx.z * R * C;
  dst += (size_t)blockIdx.z * R * C;
  const int c0 = blockIdx.x * 64, r0 = blockIdx.y * 64;
  const int t = threadIdx.x;
  const int rr = t >> 4;            // 0..15
  const int cc = (t & 15) * 4;
#pragma unroll
  for (int it = 0; it < 4; ++it) {
    int r = it * 16 + rr;
    float4 v = *(const float4*)(src + (size_t)(r0 + r) * C + c0 + cc);
    tile[cc + 0][r] = f2b(v.x);
    tile[cc + 1][r] = f2b(v.y);
    tile[cc + 2][r] = f2b(v.z);
    tile[cc + 3][r] = f2b(v.w);
  }
  __syncthreads();
  const int orow = t >> 2;          // 0..63
  const int och  = (t & 3) * 16;    // 16 bf16 per thread
  u16* dp = dst + (size_t)(c0 + orow) * R + r0 + och;
  *(bvec8*)(dp + 0) = *(const bvec8*)&tile[orow][och + 0];
  *(bvec8*)(dp + 8) = *(const bvec8*)&tile[orow][och + 8];
}

// ---------------- GEMM1: h = silu(Xg @ w1) * (Xg @ w3), grouped by expert ---------------
// A: gathered x rows (bf16, K-contig). B: w1t/w3t [E][F][H] (K-contig). Out: h bf16.
__launch_bounds__(256, 2)
__global__ void gemm1_kernel(const u16* __restrict__ xb, const u16* __restrict__ w1t,
                             const u16* __restrict__ w3t, const int* __restrict__ rowmap,
                             const int4* __restrict__ tilemap, u16* __restrict__ hbuf) {
  int4 ti = tilemap[blockIdx.y];
  if (ti.x < 0) return;
  const int e = ti.x, rowbase = ti.y, mvalid = ti.z;
  const int n0 = blockIdx.x * BN;

  __shared__ __attribute__((aligned(16))) u16 As[BM * APAD];
  __shared__ __attribute__((aligned(16))) u16 Bg[BN * APAD];
  __shared__ __attribute__((aligned(16))) u16 Bu[BN * APAD];

  const int tid = threadIdx.x;
  const int ch = tid & 3;                      // 16B chunk (8 bf16) within 32-elem row
  const int r0 = tid >> 2;                     // rows 0..63
  const int r1 = r0 + 64;                      // rows 64..127

  const int tok0 = rowmap[min(rowbase + r0, RTOT - 1)];
  const int tok1 = rowmap[min(rowbase + r1, RTOT - 1)];
  const u16* gA0 = xb + (size_t)tok0 * HID + ch * 8;
  const u16* gA1 = xb + (size_t)tok1 * HID + ch * 8;
  const u16* b1 = w1t + (size_t)e * FFN * HID + (size_t)n0 * HID + ch * 8;
  const u16* b3 = w3t + (size_t)e * FFN * HID + (size_t)n0 * HID + ch * 8;
  const u16* gB10 = b1 + (size_t)r0 * HID;
  const u16* gB11 = b1 + (size_t)r1 * HID;
  const u16* gB30 = b3 + (size_t)r0 * HID;
  const u16* gB31 = b3 + (size_t)r1 * HID;

  u16* sA0 = &As[r0 * APAD + ch * 8];
  u16* sA1 = &As[r1 * APAD + ch * 8];
  u16* sG0 = &Bg[r0 * APAD + ch * 8];
  u16* sG1 = &Bg[r1 * APAD + ch * 8];
  u16* sU0 = &Bu[r0 * APAD + ch * 8];
  u16* sU1 = &Bu[r1 * APAD + ch * 8];

  const int lane = tid & 63;
  const int wm = (tid >> 7) & 1, wn = (tid >> 6) & 1;   // 2x2 waves, 64x64 each
  const int l15 = lane & 15;
  const int kg8 = (lane >> 4) * 8;

  fvec4 accg[4][4] = {};
  fvec4 accu[4][4] = {};

  for (int kt = 0; kt < HID / BK; ++kt) {
    const int ko = kt * BK;
    bvec8 va0 = *(const bvec8*)(gA0 + ko);
    bvec8 va1 = *(const bvec8*)(gA1 + ko);
    bvec8 v10 = *(const bvec8*)(gB10 + ko);
    bvec8 v11 = *(const bvec8*)(gB11 + ko);
    bvec8 v30 = *(const bvec8*)(gB30 + ko);
    bvec8 v31 = *(const bvec8*)(gB31 + ko);
    __syncthreads();
    *(bvec8*)sA0 = va0; *(bvec8*)sA1 = va1;
    *(bvec8*)sG0 = v10; *(bvec8*)sG1 = v11;
    *(bvec8*)sU0 = v30; *(bvec8*)sU1 = v31;
    __syncthreads();
    bvec8 a[4];
#pragma unroll
    for (int mi = 0; mi < 4; ++mi)
      a[mi] = *(const bvec8*)&As[(wm * 64 + mi * 16 + l15) * APAD + kg8];
#pragma unroll
    for (int ni = 0; ni < 4; ++ni) {
      bvec8 bg = *(const bvec8*)&Bg[(wn * 64 + ni * 16 + l15) * APAD + kg8];
      bvec8 bu = *(const bvec8*)&Bu[(wn * 64 + ni * 16 + l15) * APAD + kg8];
#pragma unroll
      for (int mi = 0; mi < 4; ++mi) {
        accg[mi][ni] = __builtin_amdgcn_mfma_f32_16x16x32_bf16(a[mi], bg, accg[mi][ni], 0, 0, 0);
        accu[mi][ni] = __builtin_amdgcn_mfma_f32_16x16x32_bf16(a[mi], bu, accu[mi][ni], 0, 0, 0);
      }
    }
  }
  // epilogue: h = silu(g) * u, bf16
  const int rg4 = (lane >> 4) * 4;
#pragma unroll
  for (int mi = 0; mi < 4; ++mi) {
#pragma unroll
    for (int j = 0; j < 4; ++j) {
      int ml = wm * 64 + mi * 16 + rg4 + j;
      if (ml < mvalid) {
        size_t rowoff = (size_t)(rowbase + ml) * FFN + n0 + wn * 64;
#pragma unroll
        for (int ni = 0; ni < 4; ++ni) {
          float g = accg[mi][ni][j], u = accu[mi][ni][j];
          float hv = (g / (1.f + expf(-g))) * u;
          hbuf[rowoff + ni * 16 + l15] = f2b(hv);
        }
      }
    }
  }
}

// ---------------- GEMM2: out[token] += weight * (h @ w2), grouped by expert -------------
__launch_bounds__(256, 2)
__global__ void gemm2_kernel(const u16* __restrict__ hbuf, const u16* __restrict__ w2t,
                             const int* __restrict__ rowmap, const float* __restrict__ roww,
                             const int4* __restrict__ tilemap, float* __restrict__ out) {
  int4 ti = tilemap[blockIdx.y];
  if (ti.x < 0) return;
  const int e = ti.x, rowbase = ti.y, mvalid = ti.z;
  const int n0 = blockIdx.x * BN;

  __shared__ __attribute__((aligned(16))) u16 As[BM * APAD];
  __shared__ __attribute__((aligned(16))) u16 Bs[BN * APAD];

  const int tid = threadIdx.x;
  const int ch = tid & 3;
  const int r0 = tid >> 2;
  const int r1 = r0 + 64;

  const u16* gA0 = hbuf + (size_t)min(rowbase + r0, RTOT - 1) * FFN + ch * 8;
  const u16* gA1 = hbuf + (size_t)min(rowbase + r1, RTOT - 1) * FFN + ch * 8;
  const u16* bb = w2t + (size_t)e * HID * FFN + (size_t)n0 * FFN + ch * 8;
  const u16* gB0 = bb + (size_t)r0 * FFN;
  const u16* gB1 = bb + (size_t)r1 * FFN;

  u16* sA0 = &As[r0 * APAD + ch * 8];
  u16* sA1 = &As[r1 * APAD + ch * 8];
  u16* sB0 = &Bs[r0 * APAD + ch * 8];
  u16* sB1 = &Bs[r1 * APAD + ch * 8];

  const int lane = tid & 63;
  const int wm = (tid >> 7) & 1, wn = (tid >> 6) & 1;
  const int l15 = lane & 15;
  const int kg8 = (lane >> 4) * 8;

  fvec4 acc[4][4] = {};

  for (int kt = 0; kt < FFN / BK; ++kt) {
    const int ko = kt * BK;
    bvec8 va0 = *(const bvec8*)(gA0 + ko);
    bvec8 va1 = *(const bvec8*)(gA1 + ko);
    bvec8 vb0 = *(const bvec8*)(gB0 + ko);
    bvec8 vb1 = *(const bvec8*)(gB1 + ko);
    __syncthreads();
    *(bvec8*)sA0 = va0; *(bvec8*)sA1 = va1;
    *(bvec8*)sB0 = vb0; *(bvec8*)sB1 = vb1;
    __syncthreads();
    bvec8 a[4];
#pragma unroll
    for (int mi = 0; mi < 4; ++mi)
      a[mi] = *(const bvec8*)&As[(wm * 64 + mi * 16 + l15) * APAD + kg8];
#pragma unroll
    for (int ni = 0; ni < 4; ++ni) {
      bvec8 b = *(const bvec8*)&Bs[(wn * 64 + ni * 16 + l15) * APAD + kg8];
#pragma unroll
      for (int mi = 0; mi < 4; ++mi)
        acc[mi][ni] = __builtin_amdgcn_mfma_f32_16x16x32_bf16(a[mi], b, acc[mi][ni], 0, 0, 0);
    }
  }
  // epilogue: weighted atomic combine into out[token]
  const int rg4 = (lane >> 4) * 4;
#pragma unroll
  for (int mi = 0; mi < 4; ++mi) {
#pragma unroll
    for (int j = 0; j < 4; ++j) {
      int ml = wm * 64 + mi * 16 + rg4 + j;
      if (ml < mvalid) {
        int r = rowbase + ml;
        int tk = rowmap[r];
        float wgt = roww[r];
        float* op = out + (size_t)tk * HID + n0 + wn * 64;
#pragma unroll
        for (int ni = 0; ni < 4; ++ni)
          atomicAdd(&op[ni * 16 + l15], acc[mi][ni][j] * wgt);
      }
    }
  }
}

// ---------------- launcher --------------------------------------------------------------
extern "C" void kernel_launch(void* const* d_in, const int* in_sizes, int n_in,
                              void* d_out, int out_size, void* d_ws, size_t ws_size,
                              hipStream_t stream) {
  (void)in_sizes; (void)n_in; (void)out_size;
  const float* x  = (const float*)d_in[0];
  const float* gw = (const float*)d_in[1];
  const float* w1 = (const float*)d_in[2];
  const float* w2 = (const float*)d_in[3];   // NOTE: dict order is w1, w2, w3
  const float* w3 = (const float*)d_in[4];
  float* out = (float*)d_out;
  float* logits = out + (size_t)T_TOK * HID;

  size_t off = 0;
  auto take = [&](size_t b) { size_t o = off; off += (b + 255) & ~(size_t)255; return o; };
  size_t o_xb   = take((size_t)T_TOK * HID * 2);           // x bf16
  size_t o_wt   = take((size_t)2 * NEXP * FFN * HID * 2);  // w1t + w3t (w2t reuses front)
  size_t o_hb   = take((size_t)RTOT * FFN * 2);            // h bf16
  size_t o_rmap = take((size_t)RTOT * 4);
  size_t o_rw   = take((size_t)RTOT * 4);
  size_t o_tid  = take((size_t)RTOT * 4);
  size_t o_tw   = take((size_t)RTOT * 4);
  size_t o_cnt  = take(4 * NEXP);
  size_t o_ofs  = take(4 * (NEXP + 1));
  size_t o_cur  = take(4 * NEXP);
  size_t o_tmap = take(MAXT * 16);
  size_t total = off;

  hipMemsetAsync(d_out, 0, (size_t)T_TOK * HID * sizeof(float), stream);
  if (ws_size < total) {
    // ws too small: still produce exact logits; final_hidden stays 0 (diagnostic failure)
    router_kernel<<<T_TOK / 4, 256, 0, stream>>>(x, gw, logits, nullptr, nullptr, nullptr, 0);
    return;
  }

  char* w = (char*)d_ws;
  u16* xb   = (u16*)(w + o_xb);
  u16* w1t  = (u16*)(w + o_wt);
  u16* w3t  = w1t + (size_t)NEXP * FFN * HID;
  u16* w2t  = w1t;                                  // reused after gemm1 completes
  u16* hb   = (u16*)(w + o_hb);
  int*   rmap = (int*)(w + o_rmap);
  float* rw   = (float*)(w + o_rw);
  int*   tkid = (int*)(w + o_tid);
  float* tkw  = (float*)(w + o_tw);
  int*   cnt  = (int*)(w + o_cnt);
  int*   ofs  = (int*)(w + o_ofs);
  int*   cur  = (int*)(w + o_cur);
  int4*  tmap = (int4*)(w + o_tmap);

  hipMemsetAsync(cnt, 0, 4 * NEXP, stream);
  router_kernel<<<T_TOK / 4, 256, 0, stream>>>(x, gw, logits, tkid, tkw, cnt, 1);
  scan_kernel<<<1, 64, 0, stream>>>(cnt, ofs, cur, tmap);
  scatter_kernel<<<RTOT / 256, 256, 0, stream>>>(tkid, tkw, ofs, cur, rmap, rw);
  cast_x_kernel<<<(T_TOK * HID / 4) / 256, 256, 0, stream>>>(x, xb);
  transpose_cast_kernel<<<dim3(FFN / 64, HID / 64, NEXP), 256, 0, stream>>>(w1, w1t, HID, FFN);
  transpose_cast_kernel<<<dim3(FFN / 64, HID / 64, NEXP), 256, 0, stream>>>(w3, w3t, HID, FFN);
  gemm1_kernel<<<dim3(FFN / BN, MAXT), 256, 0, stream>>>(xb, w1t, w3t, rmap, tmap, hb);
  transpose_cast_kernel<<<dim3(HID / 64, FFN / 64, NEXP), 256, 0, stream>>>(w2, w2t, FFN, HID);
  gemm2_kernel<<<dim3(HID / BN, MAXT), 256, 0, stream>>>(hb, w2t, rmap, rw, tmap, out);
}

// Round 2
// 535.259 us; speedup vs baseline: 1.0605x; 1.0605x over previous
//
#include <hip/hip_runtime.h>
#include <hip/hip_bf16.h>
#include <cstdint>
#include <cstddef>

#define T_TOK 4096
#define HID   1024
#define FFN   3584
#define NEXP  8
#define RTOT  (T_TOK * 2)   // total (token, slot) rows = T * top_k
#define MAXT  72            // max M-tiles: floor(8192/128) + 7 = 71, +1 slack
#define BM 128
#define BN 128
#define BK 32
#define NT1 (FFN / BN)      // 28 N-tiles for gemm1
#define NT2 (HID / BN)      // 8 N-tiles for gemm2

typedef __attribute__((ext_vector_type(8))) short bvec8;   // 8 x bf16 (4 VGPR) MFMA operand
typedef __attribute__((ext_vector_type(4))) short bvec4;
typedef __attribute__((ext_vector_type(4))) float fvec4;   // MFMA accumulator
typedef unsigned short u16;

__device__ __forceinline__ u16 f2b(float f) {
  __bf16 b = (__bf16)f;                 // RNE convert
  return __builtin_bit_cast(u16, b);
}

// async global->LDS, 16B per lane. LDS dest must be wave-uniform base (HW adds lane*16).
__device__ __forceinline__ void gload16(const u16* g, u16* l) {
  __builtin_amdgcn_global_load_lds((const __attribute__((address_space(1))) void*)g,
                                   (__attribute__((address_space(3))) void*)l, 16, 0, 0);
}

// bijective XCD swizzle (m204): contiguous chunk of work per XCD
__device__ __forceinline__ int xcd_swz(int bid, int nwg) {
  int q = nwg >> 3, r = nwg & 7;
  int xcd = bid & 7, sub = bid >> 3;
  return (xcd < r ? xcd * (q + 1) : r * (q + 1) + (xcd - r) * q) + sub;
}

// ---------------- router: logits (fp32, exact), top-2, combine weights, expert counts ----
__global__ void router_kernel(const float* __restrict__ x, const float* __restrict__ gw,
                              float* __restrict__ logits, int* __restrict__ tk_id,
                              float* __restrict__ tk_w, int* __restrict__ counts, int full) {
  const int lane = threadIdx.x & 63;
  const int wid  = threadIdx.x >> 6;
  const int t = blockIdx.x * 4 + wid;          // one token per wave
  const float4* xr = (const float4*)(x + (size_t)t * HID);
  float acc[NEXP] = {0.f, 0.f, 0.f, 0.f, 0.f, 0.f, 0.f, 0.f};
#pragma unroll
  for (int it = 0; it < 4; ++it) {
    int k4 = it * 64 + lane;                   // float4 index, covers H/4 = 256
    float4 xv = xr[k4];
    const float* gp = gw + (size_t)k4 * 4 * NEXP;
    float xs[4] = {xv.x, xv.y, xv.z, xv.w};
#pragma unroll
    for (int kk = 0; kk < 4; ++kk) {
      float4 ga = ((const float4*)(gp + kk * NEXP))[0];
      float4 gb = ((const float4*)(gp + kk * NEXP))[1];
      acc[0] += xs[kk] * ga.x; acc[1] += xs[kk] * ga.y;
      acc[2] += xs[kk] * ga.z; acc[3] += xs[kk] * ga.w;
      acc[4] += xs[kk] * gb.x; acc[5] += xs[kk] * gb.y;
      acc[6] += xs[kk] * gb.z; acc[7] += xs[kk] * gb.w;
    }
  }
#pragma unroll
  for (int off = 32; off > 0; off >>= 1) {
#pragma unroll
    for (int e = 0; e < NEXP; ++e) acc[e] += __shfl_xor(acc[e], off, 64);
  }
  if (lane < NEXP) logits[(size_t)t * NEXP + lane] = acc[lane];
  if (full && lane == 0) {
    int e0 = 0; float l0 = acc[0];
#pragma unroll
    for (int e = 1; e < NEXP; ++e) if (acc[e] > l0) { l0 = acc[e]; e0 = e; }
    int e1 = -1; float l1 = -3.4e38f;
#pragma unroll
    for (int e = 0; e < NEXP; ++e) if (e != e0 && acc[e] > l1) { l1 = acc[e]; e1 = e; }
    float w0 = 1.f / (1.f + expf(l1 - l0));
    float w1 = 1.f - w0;
    tk_id[t * 2 + 0] = e0; tk_id[t * 2 + 1] = e1;
    tk_w[t * 2 + 0] = w0;  tk_w[t * 2 + 1] = w1;
    atomicAdd(&counts[e0], 1); atomicAdd(&counts[e1], 1);
  }
}

// ---------------- scan: offsets, tile map (single thread; 8 experts, trivial) -----------
__global__ void scan_kernel(const int* __restrict__ counts, int* __restrict__ offsets,
                            int* __restrict__ cursors, int4* __restrict__ tilemap) {
  if (threadIdx.x != 0) return;
  int off = 0, nt = 0;
  for (int e = 0; e < NEXP; ++e) {
    offsets[e] = off; cursors[e] = 0;
    int c = counts[e];
    for (int tm = 0; tm * BM < c; ++tm)
      tilemap[nt++] = make_int4(e, off + tm * BM, min(BM, c - tm * BM), 0);
    off += c;
  }
  offsets[NEXP] = off;
  for (; nt < MAXT; ++nt) tilemap[nt] = make_int4(-1, 0, 0, 0);
}

// ---------------- scatter: build per-expert sorted row lists ----------------------------
__global__ void scatter_kernel(const int* __restrict__ tk_id, const float* __restrict__ tk_w,
                               const int* __restrict__ offsets, int* __restrict__ cursors,
                               int* __restrict__ rowmap, float* __restrict__ roww) {
  int i = blockIdx.x * 256 + threadIdx.x;      // 0 .. RTOT-1
  int t = i >> 1;
  int e = tk_id[i]; float w = tk_w[i];
  int p = atomicAdd(&cursors[e], 1);
  rowmap[offsets[e] + p] = t; roww[offsets[e] + p] = w;
}

// ---------------- cast x to bf16 --------------------------------------------------------
__global__ void cast_x_kernel(const float* __restrict__ x, u16* __restrict__ xb) {
  size_t i = (size_t)blockIdx.x * 256 + threadIdx.x;   // one float4 each
  float4 v = ((const float4*)x)[i];
  bvec4 o;
  o[0] = (short)f2b(v.x); o[1] = (short)f2b(v.y);
  o[2] = (short)f2b(v.z); o[3] = (short)f2b(v.w);
  *(bvec4*)(xb + i * 4) = o;
}

// ---------------- transpose + cast: fp32 [R][C] -> bf16 [C][R], batched by blockIdx.z ---
__global__ void transpose_cast_kernel(const float* __restrict__ src, u16* __restrict__ dst,
                                      int R, int C) {
  __shared__ __attribute__((aligned(16))) u16 tile[64][72];
  src += (size_t)blockIdx.z * R * C;
  dst += (size_t)blockIdx.z * R * C;
  const int c0 = blockIdx.x * 64, r0 = blockIdx.y * 64;
  const int t = threadIdx.x;
  const int rr = t >> 4;            // 0..15
  const int cc = (t & 15) * 4;
#pragma unroll
  for (int it = 0; it < 4; ++it) {
    int r = it * 16 + rr;
    float4 v = *(const float4*)(src + (size_t)(r0 + r) * C + c0 + cc);
    tile[cc + 0][r] = f2b(v.x);
    tile[cc + 1][r] = f2b(v.y);
    tile[cc + 2][r] = f2b(v.z);
    tile[cc + 3][r] = f2b(v.w);
  }
  __syncthreads();
  const int orow = t >> 2;          // 0..63
  const int och  = (t & 3) * 16;
  u16* dp = dst + (size_t)(c0 + orow) * R + r0 + och;
  *(bvec8*)(dp + 0) = *(const bvec8*)&tile[orow][och + 0];
  *(bvec8*)(dp + 8) = *(const bvec8*)&tile[orow][och + 8];
}

// ---------------- GEMM1: h = silu(Xg @ w1) * (Xg @ w3), grouped by expert ---------------
// m97 structure: global_load_lds(16B) staging, linear LDS [128][32], 2 barriers/K-step.
// Bank-conflict fix: per-lane pre-swizzled global source chunk + swizzled ds_read chunk
// (involution: chunk ^= (row>>1)&3 within each row's four 16B chunks).
__launch_bounds__(256, 2)
__global__ void gemm1_kernel(const u16* __restrict__ xb, const u16* __restrict__ w1t,
                             const u16* __restrict__ w3t, const int* __restrict__ rowmap,
                             const int4* __restrict__ tilemap, u16* __restrict__ hbuf) {
  const int wg = xcd_swz(blockIdx.x, NT1 * MAXT);
  const int mt = wg % MAXT;          // M fastest within an XCD chunk -> B-panel L2 reuse
  const int nt = wg / MAXT;
  int4 ti = tilemap[mt];
  if (ti.x < 0) return;
  const int e = ti.x, rowbase = ti.y, mvalid = ti.z;
  const int n0 = nt * BN;

  __shared__ __attribute__((aligned(128))) u16 As[BM * BK];
  __shared__ __attribute__((aligned(128))) u16 Bg[BN * BK];
  __shared__ __attribute__((aligned(128))) u16 Bu[BN * BK];

  const int tid = threadIdx.x;
  const int lane = tid & 63;
  const int w = tid >> 6;

  // staging geometry: each 1KB LDS chunk = 16 rows x 32 bf16; lane l -> row l>>2, phys chunk l&3
  const int r16 = lane >> 2;
  const int csrc = ((lane & 3) ^ ((lane >> 3) & 3)) * 8;   // swizzled source chunk (elems)
  const int rA0 = w * 16 + r16, rA1 = 64 + w * 16 + r16;
  const int tokA0 = rowmap[min(rowbase + rA0, RTOT - 1)];
  const int tokA1 = rowmap[min(rowbase + rA1, RTOT - 1)];
  const u16* gA0 = xb + (size_t)tokA0 * HID + csrc;
  const u16* gA1 = xb + (size_t)tokA1 * HID + csrc;
  const u16* wb1 = w1t + (size_t)e * FFN * HID;
  const u16* wb3 = w3t + (size_t)e * FFN * HID;
  const u16* gG0 = wb1 + (size_t)(n0 + rA0) * HID + csrc;
  const u16* gG1 = wb1 + (size_t)(n0 + rA1) * HID + csrc;
  const u16* gU0 = wb3 + (size_t)(n0 + rA0) * HID + csrc;
  const u16* gU1 = wb3 + (size_t)(n0 + rA1) * HID + csrc;

  u16* lA0 = &As[(w * 16) * BK];       // wave-uniform dests
  u16* lA1 = &As[(64 + w * 16) * BK];
  u16* lG0 = &Bg[(w * 16) * BK];
  u16* lG1 = &Bg[(64 + w * 16) * BK];
  u16* lU0 = &Bu[(w * 16) * BK];
  u16* lU1 = &Bu[(64 + w * 16) * BK];

  const int wm = (tid >> 7) & 1, wn = (tid >> 6) & 1;   // 2x2 waves, 64x64 each
  const int l15 = lane & 15;
  const int pkg8 = (((lane >> 4) ^ ((lane >> 1) & 3)) << 3);  // swizzled read chunk (elems)
  const int iA = (wm * 64 + l15) * BK + pkg8;   // + mi*16*BK
  const int iB = (wn * 64 + l15) * BK + pkg8;   // + ni*16*BK

  fvec4 accg[4][4] = {};
  fvec4 accu[4][4] = {};

  for (int kt = 0; kt < HID / BK; ++kt) {
    gload16(gA0, lA0); gload16(gA1, lA1);
    gload16(gG0, lG0); gload16(gG1, lG1);
    gload16(gU0, lU0); gload16(gU1, lU1);
    gA0 += BK; gA1 += BK; gG0 += BK; gG1 += BK; gU0 += BK; gU1 += BK;
    __syncthreads();                         // vmcnt(0) drain: LDS tile ready
    bvec8 a[4];
#pragma unroll
    for (int mi = 0; mi < 4; ++mi)
      a[mi] = *(const bvec8*)&As[iA + mi * 16 * BK];
#pragma unroll
    for (int ni = 0; ni < 4; ++ni) {
      bvec8 bg = *(const bvec8*)&Bg[iB + ni * 16 * BK];
      bvec8 bu = *(const bvec8*)&Bu[iB + ni * 16 * BK];
#pragma unroll
      for (int mi = 0; mi < 4; ++mi) {
        accg[mi][ni] = __builtin_amdgcn_mfma_f32_16x16x32_bf16(a[mi], bg, accg[mi][ni], 0, 0, 0);
        accu[mi][ni] = __builtin_amdgcn_mfma_f32_16x16x32_bf16(a[mi], bu, accu[mi][ni], 0, 0, 0);
      }
    }
    __syncthreads();                         // all reads done before next overwrite
  }
  // epilogue: h = silu(g) * u, bf16
  const int rg4 = (lane >> 4) * 4;
#pragma unroll
  for (int mi = 0; mi < 4; ++mi) {
#pragma unroll
    for (int j = 0; j < 4; ++j) {
      int ml = wm * 64 + mi * 16 + rg4 + j;
      if (ml < mvalid) {
        size_t rowoff = (size_t)(rowbase + ml) * FFN + n0 + wn * 64;
#pragma unroll
        for (int ni = 0; ni < 4; ++ni) {
          float g = accg[mi][ni][j], u = accu[mi][ni][j];
          float hv = (g / (1.f + expf(-g))) * u;
          hbuf[rowoff + ni * 16 + l15] = f2b(hv);
        }
      }
    }
  }
}

// ---------------- GEMM2: out[token] += weight * (h @ w2), grouped by expert -------------
__launch_bounds__(256, 3)
__global__ void gemm2_kernel(const u16* __restrict__ hbuf, const u16* __restrict__ w2t,
                             const int* __restrict__ rowmap, const float* __restrict__ roww,
                             const int4* __restrict__ tilemap, float* __restrict__ out) {
  const int wg = xcd_swz(blockIdx.x, NT2 * MAXT);
  const int mt = wg % MAXT;
  const int nt = wg / MAXT;
  int4 ti = tilemap[mt];
  if (ti.x < 0) return;
  const int e = ti.x, rowbase = ti.y, mvalid = ti.z;
  const int n0 = nt * BN;

  __shared__ __attribute__((aligned(128))) u16 As[BM * BK];
  __shared__ __attribute__((aligned(128))) u16 Bs[BN * BK];

  const int tid = threadIdx.x;
  const int lane = tid & 63;
  const int w = tid >> 6;

  const int r16 = lane >> 2;
  const int csrc = ((lane & 3) ^ ((lane >> 3) & 3)) * 8;
  const int rA0 = w * 16 + r16, rA1 = 64 + w * 16 + r16;
  const u16* gA0 = hbuf + (size_t)min(rowbase + rA0, RTOT - 1) * FFN + csrc;
  const u16* gA1 = hbuf + (size_t)min(rowbase + rA1, RTOT - 1) * FFN + csrc;
  const u16* wb2 = w2t + (size_t)e * HID * FFN;
  const u16* gB0 = wb2 + (size_t)(n0 + rA0) * FFN + csrc;
  const u16* gB1 = wb2 + (size_t)(n0 + rA1) * FFN + csrc;

  u16* lA0 = &As[(w * 16) * BK];
  u16* lA1 = &As[(64 + w * 16) * BK];
  u16* lB0 = &Bs[(w * 16) * BK];
  u16* lB1 = &Bs[(64 + w * 16) * BK];

  const int wm = (tid >> 7) & 1, wn = (tid >> 6) & 1;
  const int l15 = lane & 15;
  const int pkg8 = (((lane >> 4) ^ ((lane >> 1) & 3)) << 3);
  const int iA = (wm * 64 + l15) * BK + pkg8;
  const int iB = (wn * 64 + l15) * BK + pkg8;

  fvec4 acc[4][4] = {};

  for (int kt = 0; kt < FFN / BK; ++kt) {
    gload16(gA0, lA0); gload16(gA1, lA1);
    gload16(gB0, lB0); gload16(gB1, lB1);
    gA0 += BK; gA1 += BK; gB0 += BK; gB1 += BK;
    __syncthreads();
    bvec8 a[4];
#pragma unroll
    for (int mi = 0; mi < 4; ++mi)
      a[mi] = *(const bvec8*)&As[iA + mi * 16 * BK];
#pragma unroll
    for (int ni = 0; ni < 4; ++ni) {
      bvec8 b = *(const bvec8*)&Bs[iB + ni * 16 * BK];
#pragma unroll
      for (int mi = 0; mi < 4; ++mi)
        acc[mi][ni] = __builtin_amdgcn_mfma_f32_16x16x32_bf16(a[mi], b, acc[mi][ni], 0, 0, 0);
    }
    __syncthreads();
  }
  // epilogue: weighted atomic combine into out[token]
  const int rg4 = (lane >> 4) * 4;
#pragma unroll
  for (int mi = 0; mi < 4; ++mi) {
#pragma unroll
    for (int j = 0; j < 4; ++j) {
      int ml = wm * 64 + mi * 16 + rg4 + j;
      if (ml < mvalid) {
        int r = rowbase + ml;
        int tk = rowmap[r];
        float wgt = roww[r];
        float* op = out + (size_t)tk * HID + n0 + wn * 64;
#pragma unroll
        for (int ni = 0; ni < 4; ++ni)
          atomicAdd(&op[ni * 16 + l15], acc[mi][ni][j] * wgt);
      }
    }
  }
}

// ---------------- launcher --------------------------------------------------------------
extern "C" void kernel_launch(void* const* d_in, const int* in_sizes, int n_in,
                              void* d_out, int out_size, void* d_ws, size_t ws_size,
                              hipStream_t stream) {
  (void)in_sizes; (void)n_in; (void)out_size;
  const float* x  = (const float*)d_in[0];
  const float* gw = (const float*)d_in[1];
  const float* w1 = (const float*)d_in[2];
  const float* w2 = (const float*)d_in[3];   // NOTE: dict order is w1, w2, w3
  const float* w3 = (const float*)d_in[4];
  float* out = (float*)d_out;
  float* logits = out + (size_t)T_TOK * HID;

  size_t off = 0;
  auto take = [&](size_t b) { size_t o = off; off += (b + 255) & ~(size_t)255; return o; };
  size_t o_xb   = take((size_t)T_TOK * HID * 2);           // x bf16
  size_t o_wt   = take((size_t)2 * NEXP * FFN * HID * 2);  // w1t + w3t (w2t reuses front)
  size_t o_hb   = take((size_t)RTOT * FFN * 2);            // h bf16
  size_t o_rmap = take((size_t)RTOT * 4);
  size_t o_rw   = take((size_t)RTOT * 4);
  size_t o_tid  = take((size_t)RTOT * 4);
  size_t o_tw   = take((size_t)RTOT * 4);
  size_t o_cnt  = take(4 * NEXP);
  size_t o_ofs  = take(4 * (NEXP + 1));
  size_t o_cur  = take(4 * NEXP);
  size_t o_tmap = take(MAXT * 16);
  size_t total = off;

  hipMemsetAsync(d_out, 0, (size_t)T_TOK * HID * sizeof(float), stream);
  if (ws_size < total) {
    router_kernel<<<T_TOK / 4, 256, 0, stream>>>(x, gw, logits, nullptr, nullptr, nullptr, 0);
    return;
  }

  char* w = (char*)d_ws;
  u16* xb   = (u16*)(w + o_xb);
  u16* w1t  = (u16*)(w + o_wt);
  u16* w3t  = w1t + (size_t)NEXP * FFN * HID;
  u16* w2t  = w1t;                                  // reused after gemm1 completes
  u16* hb   = (u16*)(w + o_hb);
  int*   rmap = (int*)(w + o_rmap);
  float* rw   = (float*)(w + o_rw);
  int*   tkid = (int*)(w + o_tid);
  float* tkw  = (float*)(w + o_tw);
  int*   cnt  = (int*)(w + o_cnt);
  int*   ofs  = (int*)(w + o_ofs);
  int*   cur  = (int*)(w + o_cur);
  int4*  tmap = (int4*)(w + o_tmap);

  hipMemsetAsync(cnt, 0, 4 * NEXP, stream);
  router_kernel<<<T_TOK / 4, 256, 0, stream>>>(x, gw, logits, tkid, tkw, cnt, 1);
  scan_kernel<<<1, 64, 0, stream>>>(cnt, ofs, cur, tmap);
  scatter_kernel<<<RTOT / 256, 256, 0, stream>>>(tkid, tkw, ofs, cur, rmap, rw);
  cast_x_kernel<<<(T_TOK * HID / 4) / 256, 256, 0, stream>>>(x, xb);
  transpose_cast_kernel<<<dim3(FFN / 64, HID / 64, NEXP), 256, 0, stream>>>(w1, w1t, HID, FFN);
  transpose_cast_kernel<<<dim3(FFN / 64, HID / 64, NEXP), 256, 0, stream>>>(w3, w3t, HID, FFN);
  gemm1_kernel<<<NT1 * MAXT, 256, 0, stream>>>(xb, w1t, w3t, rmap, tmap, hb);
  transpose_cast_kernel<<<dim3(HID / 64, FFN / 64, NEXP), 256, 0, stream>>>(w2, w2t, FFN, HID);
  gemm2_kernel<<<NT2 * MAXT, 256, 0, stream>>>(hb, w2t, rmap, rw, tmap, out);
}